// Round 10
// baseline (89.946 us; speedup 1.0000x reference)
//
#include <hip/hip_runtime.h>
#include <hip/hip_bf16.h>
#include <math.h>

#define BLOCK 256
#define ITEMS 4
#define TILE (BLOCK * ITEMS)

typedef float f4v __attribute__((ext_vector_type(4)));

__device__ __forceinline__ float compute_ratio(const float* uw, const int* timep) {
  int t = timep[0];
  t = ((t % 4) + 4) % 4;
  float base = (t == 0) ? 0.5f : (t == 1) ? 0.3f : (t == 2) ? 0.7f : 0.2f;
  double u = (double)uw[0];
  float w = (float)(-log1p(-u));  // SCALE=1, CONCENTRATION=1
  float r = base * w;
  r = fminf(fmaxf(r, 0.0f), 0.9f);
  if (r < 0.1f) r = 0.0f;
  return r;
}

// Pass A: per-thread 4-bit activity mask + per-block count; block 0 also
// detects rec/send dtype (int64 vs int32) into flagp.
__global__ __launch_bounds__(BLOCK, 8) void passA(
    const float* __restrict__ aedges, const float* __restrict__ ue,
    const float* __restrict__ uw, const int* __restrict__ timep,
    const unsigned* __restrict__ rec32, const unsigned* __restrict__ send32,
    unsigned* __restrict__ bsums, unsigned char* __restrict__ masks,
    unsigned* __restrict__ flagp, int use_masks, int E) {
  __shared__ float s_ratio;
  __shared__ unsigned s_w[BLOCK / 64];
  const int tid = threadIdx.x;
  if (tid == 0) s_ratio = compute_ratio(uw, timep);
  if (blockIdx.x == 0 && tid < 64) {  // i64-vs-i32 detection (one wave)
    unsigned acc = 0;
#pragma unroll
    for (int j = 0; j < 4; ++j) {
      const int i = tid + j * 64;
      acc |= rec32[2 * i + 1];
      acc |= send32[2 * i + 1];
    }
#pragma unroll
    for (int d = 1; d < 64; d <<= 1) acc |= __shfl_xor(acc, d);
    if (tid == 0) flagp[0] = (acc == 0u) ? 1u : 0u;
  }
  __syncthreads();
  const float ratio = s_ratio;
  const long long base = (long long)blockIdx.x * TILE + (long long)tid * ITEMS;
  unsigned m = 0;
  if (base + ITEMS <= (long long)E) {
    const f4v a0 = *(const f4v*)(aedges + base);
    const f4v u0 = *(const f4v*)(ue + base);
    const float av[4] = {a0.x, a0.y, a0.z, a0.w};
    const float uv[4] = {u0.x, u0.y, u0.z, u0.w};
#pragma unroll
    for (int j = 0; j < 4; ++j)
      if (av[j] != 0.0f && uv[j] >= ratio) m |= (1u << j);
  } else {
    for (int j = 0; j < 4; ++j) {
      long long i = base + j;
      if (i < (long long)E && aedges[i] != 0.0f && ue[i] >= ratio) m |= (1u << j);
    }
  }
  if (use_masks) masks[(size_t)blockIdx.x * BLOCK + tid] = (unsigned char)m;
  unsigned c = __popc(m);
#pragma unroll
  for (int d = 1; d < 64; d <<= 1) c += __shfl_xor(c, d);
  if ((tid & 63) == 0) s_w[tid >> 6] = c;
  __syncthreads();
  if (tid == 0) bsums[blockIdx.x] = s_w[0] + s_w[1] + s_w[2] + s_w[3];
}

// Pass C: mask -> block scan -> LDS permutation; each block computes its own
// global prefix + total from raw bsums (issued early, hidden under staging).
// Dest-ordered full-line NT writes.
__global__ __launch_bounds__(BLOCK, 8) void passC(
    const float* __restrict__ aedges, const float* __restrict__ ue,
    const float* __restrict__ uw, const int* __restrict__ timep,
    const int* __restrict__ rec32, const int* __restrict__ send32,
    const float* __restrict__ edges,
    const unsigned* __restrict__ bsums, int nblocks,
    const unsigned* __restrict__ flagp,
    const unsigned char* __restrict__ masks, int use_masks,
    float* __restrict__ out, int E, int sentinel) {
  __shared__ float s_ratio;
  __shared__ unsigned s_w[BLOCK / 64];
  __shared__ unsigned s_i64;
  __shared__ unsigned long long s_red[BLOCK / 64];
  __shared__ unsigned short s_sidx[TILE];  // dest rank -> local source index
  __shared__ unsigned short s_rec[TILE];   // dest rank -> rec id (<65536)
  __shared__ unsigned short s_send[TILE];  // dest rank -> send id (<65536)
  const int tid = threadIdx.x;
  const int b = blockIdx.x;
  if (tid == 0) { s_ratio = compute_ratio(uw, timep); s_i64 = flagp[0]; }
  __syncthreads();
  const bool is64 = (s_i64 != 0u);
  const long long tileBase = (long long)b * TILE;
  const int local_n = (int)min((long long)TILE, (long long)E - tileBase);
  const long long base = tileBase + (long long)tid * ITEMS;
  const bool full = (base + ITEMS <= (long long)E);
  const unsigned short sent16 = (unsigned short)sentinel;

  // --- global prefix + total, per block (coalesced L2 reads, issued first
  //     so the latency overlaps the staging work below) ---
  const int nk = (nblocks + BLOCK - 1) / BLOCK;
  unsigned long long pr = 0;  // low 32: prefix before b; high 32: total
  for (int k = 0; k < nk; ++k) {
    const int idx = tid + k * BLOCK;
    const unsigned v = (idx < nblocks) ? bsums[idx] : 0u;
    pr += ((unsigned long long)v << 32);
    if (idx < b) pr += v;
  }
#pragma unroll
  for (int d = 1; d < 64; d <<= 1) pr += __shfl_xor(pr, d);
  if ((tid & 63) == 0) s_red[tid >> 6] = pr;

  // --- activity mask ---
  unsigned m = 0;
  if (use_masks) {
    m = (unsigned)masks[(size_t)b * BLOCK + tid];
  } else {
    const float ratio = s_ratio;
    if (full) {
      const f4v a0 = *(const f4v*)(aedges + base);
      const f4v u0 = *(const f4v*)(ue + base);
      const float av[4] = {a0.x, a0.y, a0.z, a0.w};
      const float uv[4] = {u0.x, u0.y, u0.z, u0.w};
#pragma unroll
      for (int j = 0; j < 4; ++j)
        if (av[j] != 0.0f && uv[j] >= ratio) m |= (1u << j);
    } else {
      for (int j = 0; j < 4; ++j) {
        long long i = base + j;
        if (i < (long long)E && aedges[i] != 0.0f && ue[i] >= ratio) m |= (1u << j);
      }
    }
  }

  // --- block scan of active counts ---
  const unsigned c = __popc(m);
  unsigned x = c;
#pragma unroll
  for (int d = 1; d < 64; d <<= 1) {
    unsigned t = __shfl_up(x, d);
    if ((tid & 63) >= d) x += t;
  }
  if ((tid & 63) == 63) s_w[tid >> 6] = x;
  __syncthreads();
  unsigned woff = 0;
  for (int w = 0; w < (tid >> 6); ++w) woff += s_w[w];
  const unsigned cnt = s_w[0] + s_w[1] + s_w[2] + s_w[3];
  const unsigned thread_excl = woff + (x - c);

  // --- staging: branchless vectorized rec/send + LDS permutation ---
  unsigned short rvs[ITEMS], svs[ITEMS];
  if (full && is64) {
    const long long* rp = (const long long*)rec32 + base;
    const long long* sp = (const long long*)send32 + base;
    const ulonglong2 r01 = *(const ulonglong2*)rp;
    const ulonglong2 r23 = *(const ulonglong2*)(rp + 2);
    const ulonglong2 t01 = *(const ulonglong2*)sp;
    const ulonglong2 t23 = *(const ulonglong2*)(sp + 2);
    rvs[0] = (unsigned short)r01.x; rvs[1] = (unsigned short)r01.y;
    rvs[2] = (unsigned short)r23.x; rvs[3] = (unsigned short)r23.y;
    svs[0] = (unsigned short)t01.x; svs[1] = (unsigned short)t01.y;
    svs[2] = (unsigned short)t23.x; svs[3] = (unsigned short)t23.y;
  } else if (full) {
    const uint4 rr = *(const uint4*)((const unsigned*)rec32 + base);
    const uint4 ss = *(const uint4*)((const unsigned*)send32 + base);
    rvs[0] = (unsigned short)rr.x; rvs[1] = (unsigned short)rr.y;
    rvs[2] = (unsigned short)rr.z; rvs[3] = (unsigned short)rr.w;
    svs[0] = (unsigned short)ss.x; svs[1] = (unsigned short)ss.y;
    svs[2] = (unsigned short)ss.z; svs[3] = (unsigned short)ss.w;
  } else {
#pragma unroll
    for (int j = 0; j < 4; ++j) {
      const long long i = base + j;
      unsigned short rv = sent16, sv = sent16;
      if (i < (long long)E) {
        if (is64) {
          rv = (unsigned short)((const long long*)rec32)[i];
          sv = (unsigned short)((const long long*)send32)[i];
        } else {
          rv = (unsigned short)rec32[i];
          sv = (unsigned short)send32[i];
        }
      }
      rvs[j] = rv; svs[j] = sv;
    }
  }
#pragma unroll
  for (int j = 0; j < ITEMS; ++j) {
    const int li = tid * ITEMS + j;
    if (li >= local_n) break;
    const bool act = ((m >> j) & 1u) != 0u;
    const unsigned rb = __popc(m & ((1u << j) - 1u));
    const unsigned actsBefore = thread_excl + rb;
    const unsigned dr = act ? actsBefore : (cnt + ((unsigned)li - actsBefore));
    s_sidx[dr] = (unsigned short)li;
    s_rec[dr] = act ? rvs[j] : sent16;
    s_send[dr] = act ? svs[j] : sent16;
  }
  __syncthreads();

  const unsigned long long tt = s_red[0] + s_red[1] + s_red[2] + s_red[3];
  const unsigned gA = (unsigned)(tt & 0xffffffffull);
  const unsigned nA = (unsigned)(tt >> 32);
  const unsigned gI = nA + (unsigned)tileBase - gA;

  float* __restrict__ out_na = out;
  float* __restrict__ out_rec = out + (size_t)E;
  float* __restrict__ out_send = out + 2 * (size_t)E;
  float* __restrict__ out_edges = out + 3 * (size_t)E;
  const f4v zero4 = {0.f, 0.f, 0.f, 0.f};
  const int sub = tid & 3;

  if (local_n == TILE) {
#pragma unroll
    for (int k = 0; k < ITEMS; ++k) {
      const int r = tid + k * BLOCK;
      const bool ra = (unsigned)r < cnt;
      const unsigned dest = ra ? (gA + (unsigned)r) : (gI + ((unsigned)r - cnt));
      __builtin_nontemporal_store(ra ? 1.0f : 0.0f, out_na + dest);
      __builtin_nontemporal_store((float)s_rec[r], out_rec + dest);
      __builtin_nontemporal_store((float)s_send[r], out_send + dest);
    }
#pragma unroll 8
    for (int k = 0; k < TILE / (BLOCK / 4); ++k) {  // 16 iters, 4 lanes/row
      const int r = (tid >> 2) + k * (BLOCK / 4);
      const bool ra = (unsigned)r < cnt;
      const unsigned dest = ra ? (gA + (unsigned)r) : (gI + ((unsigned)r - cnt));
      f4v v = zero4;
      if (ra) {
        const int si = (int)s_sidx[r];
        v = ((const f4v*)edges)[(size_t)(tileBase + si) * 4 + sub];
      }
      __builtin_nontemporal_store(v, (f4v*)out_edges + (size_t)dest * 4 + sub);
    }
  } else {
    for (int k = 0; k < ITEMS; ++k) {
      const int r = tid + k * BLOCK;
      if (r >= local_n) break;
      const bool ra = (unsigned)r < cnt;
      const unsigned dest = ra ? (gA + (unsigned)r) : (gI + ((unsigned)r - cnt));
      out_na[dest] = ra ? 1.0f : 0.0f;
      out_rec[dest] = (float)s_rec[r];
      out_send[dest] = (float)s_send[r];
    }
    for (int k = 0; k < TILE / (BLOCK / 4); ++k) {
      const int r = (tid >> 2) + k * (BLOCK / 4);
      if (r >= local_n) break;
      const bool ra = (unsigned)r < cnt;
      const unsigned dest = ra ? (gA + (unsigned)r) : (gI + ((unsigned)r - cnt));
      f4v v = zero4;
      if (ra) {
        const int si = (int)s_sidx[r];
        v = ((const f4v*)edges)[(size_t)(tileBase + si) * 4 + sub];
      }
      ((f4v*)out_edges)[(size_t)dest * 4 + sub] = v;
    }
  }
}

extern "C" void kernel_launch(void* const* d_in, const int* in_sizes, int n_in,
                              void* d_out, int out_size, void* d_ws, size_t ws_size,
                              hipStream_t stream) {
  const float* edges = (const float*)d_in[1];
  const float* aedges = (const float*)d_in[2];
  const float* uw = (const float*)d_in[3];
  const float* ue = (const float*)d_in[4];
  const int* rec = (const int*)d_in[5];
  const int* send = (const int*)d_in[6];
  const int* timep = (const int*)d_in[7];

  const int E = in_sizes[2];
  const int n_nodes = in_sizes[0] / 128;
  const int sentinel = n_nodes - 1;
  const int nblocks = (E + TILE - 1) / TILE;

  unsigned* bsums = (unsigned*)d_ws;                     // nblocks uints (raw counts)
  unsigned* flagp = bsums + (nblocks + 2);               // dtype flag
  unsigned char* masks = (unsigned char*)(bsums + nblocks + 16);
  const size_t need = (size_t)(nblocks + 16) * 4 + (size_t)nblocks * BLOCK + 64;
  const int use_masks = (ws_size >= need) ? 1 : 0;
  float* out = (float*)d_out;

  hipLaunchKernelGGL(passA, dim3(nblocks), dim3(BLOCK), 0, stream,
                     aedges, ue, uw, timep, (const unsigned*)rec,
                     (const unsigned*)send, bsums, masks, flagp, use_masks, E);
  hipLaunchKernelGGL(passC, dim3(nblocks), dim3(BLOCK), 0, stream,
                     aedges, ue, uw, timep, rec, send, edges, bsums, nblocks,
                     flagp, masks, use_masks, out, E, sentinel);
}

// Round 11
// 83.323 us; speedup vs baseline: 1.0795x; 1.0795x over previous
//
#include <hip/hip_runtime.h>
#include <hip/hip_bf16.h>
#include <math.h>

#define BLOCK 256
#define ITEMS 4
#define TILE (BLOCK * ITEMS)

typedef float f4v __attribute__((ext_vector_type(4)));

__device__ __forceinline__ float compute_ratio(const float* uw, const int* timep) {
  int t = timep[0];
  t = ((t % 4) + 4) % 4;
  float base = (t == 0) ? 0.5f : (t == 1) ? 0.3f : (t == 2) ? 0.7f : 0.2f;
  double u = (double)uw[0];
  float w = (float)(-log1p(-u));  // SCALE=1, CONCENTRATION=1
  float r = base * w;
  r = fminf(fmaxf(r, 0.0f), 0.9f);
  if (r < 0.1f) r = 0.0f;
  return r;
}

// Pass A: per-thread 4-bit activity mask + per-block count; block 0 also
// detects rec/send dtype (int64 vs int32) into flagp.
__global__ __launch_bounds__(BLOCK, 8) void passA(
    const float* __restrict__ aedges, const float* __restrict__ ue,
    const float* __restrict__ uw, const int* __restrict__ timep,
    const unsigned* __restrict__ rec32, const unsigned* __restrict__ send32,
    unsigned* __restrict__ bsums, unsigned char* __restrict__ masks,
    unsigned* __restrict__ flagp, int use_masks, int E) {
  __shared__ float s_ratio;
  __shared__ unsigned s_w[BLOCK / 64];
  const int tid = threadIdx.x;
  if (tid == 0) s_ratio = compute_ratio(uw, timep);
  if (blockIdx.x == 0 && tid < 64) {  // i64-vs-i32 detection (one wave)
    unsigned acc = 0;
#pragma unroll
    for (int j = 0; j < 4; ++j) {
      const int i = tid + j * 64;
      acc |= rec32[2 * i + 1];
      acc |= send32[2 * i + 1];
    }
#pragma unroll
    for (int d = 1; d < 64; d <<= 1) acc |= __shfl_xor(acc, d);
    if (tid == 0) flagp[0] = (acc == 0u) ? 1u : 0u;
  }
  __syncthreads();
  const float ratio = s_ratio;
  const long long base = (long long)blockIdx.x * TILE + (long long)tid * ITEMS;
  unsigned m = 0;
  if (base + ITEMS <= (long long)E) {
    const f4v a0 = *(const f4v*)(aedges + base);
    const f4v u0 = *(const f4v*)(ue + base);
    const float av[4] = {a0.x, a0.y, a0.z, a0.w};
    const float uv[4] = {u0.x, u0.y, u0.z, u0.w};
#pragma unroll
    for (int j = 0; j < 4; ++j)
      if (av[j] != 0.0f && uv[j] >= ratio) m |= (1u << j);
  } else {
    for (int j = 0; j < 4; ++j) {
      long long i = base + j;
      if (i < (long long)E && aedges[i] != 0.0f && ue[i] >= ratio) m |= (1u << j);
    }
  }
  if (use_masks) masks[(size_t)blockIdx.x * BLOCK + tid] = (unsigned char)m;
  unsigned c = __popc(m);
#pragma unroll
  for (int d = 1; d < 64; d <<= 1) c += __shfl_xor(c, d);
  if ((tid & 63) == 0) s_w[tid >> 6] = c;
  __syncthreads();
  if (tid == 0) bsums[blockIdx.x] = s_w[0] + s_w[1] + s_w[2] + s_w[3];
}

// Pass C: mask -> block scan -> packed-u64 LDS permutation; per-block global
// prefix with DEFERRED reduce (bsums loads issued first, reduced after staging
// so L2 latency hides under real work). Dest-ordered full-line NT writes.
__global__ __launch_bounds__(BLOCK, 8) void passC(
    const float* __restrict__ aedges, const float* __restrict__ ue,
    const float* __restrict__ uw, const int* __restrict__ timep,
    const int* __restrict__ rec32, const int* __restrict__ send32,
    const float* __restrict__ edges,
    const unsigned* __restrict__ bsums, int nblocks,
    const unsigned* __restrict__ flagp,
    const unsigned char* __restrict__ masks, int use_masks,
    float* __restrict__ out, int E, int sentinel) {
  __shared__ float s_ratio;
  __shared__ unsigned s_w[BLOCK / 64];
  __shared__ unsigned s_i64;
  __shared__ unsigned long long s_red[BLOCK / 64];
  __shared__ unsigned long long s_pk[TILE];  // dest rank -> {sidx<<32|send<<16|rec}
  const int tid = threadIdx.x;
  const int b = blockIdx.x;
  if (tid == 0) { s_ratio = compute_ratio(uw, timep); s_i64 = flagp[0]; }
  __syncthreads();
  const bool is64 = (s_i64 != 0u);
  const long long tileBase = (long long)b * TILE;
  const int local_n = (int)min((long long)TILE, (long long)E - tileBase);
  const long long base = tileBase + (long long)tid * ITEMS;
  const bool full = (base + ITEMS <= (long long)E);
  const unsigned short sent16 = (unsigned short)sentinel;

  // --- issue bsums loads NOW, reduce LATER (hide L2 latency under staging) ---
  const int NK = 16;  // supports nblocks <= 4096
  unsigned bs_v[NK];
#pragma unroll
  for (int k = 0; k < NK; ++k) {
    const int idx = tid + k * BLOCK;
    bs_v[k] = (idx < nblocks) ? bsums[idx] : 0u;
  }

  // --- activity mask ---
  unsigned m = 0;
  if (use_masks) {
    m = (unsigned)masks[(size_t)b * BLOCK + tid];
  } else {
    const float ratio = s_ratio;
    if (full) {
      const f4v a0 = *(const f4v*)(aedges + base);
      const f4v u0 = *(const f4v*)(ue + base);
      const float av[4] = {a0.x, a0.y, a0.z, a0.w};
      const float uv[4] = {u0.x, u0.y, u0.z, u0.w};
#pragma unroll
      for (int j = 0; j < 4; ++j)
        if (av[j] != 0.0f && uv[j] >= ratio) m |= (1u << j);
    } else {
      for (int j = 0; j < 4; ++j) {
        long long i = base + j;
        if (i < (long long)E && aedges[i] != 0.0f && ue[i] >= ratio) m |= (1u << j);
      }
    }
  }

  // --- block scan of active counts ---
  const unsigned c = __popc(m);
  unsigned x = c;
#pragma unroll
  for (int d = 1; d < 64; d <<= 1) {
    unsigned t = __shfl_up(x, d);
    if ((tid & 63) >= d) x += t;
  }
  if ((tid & 63) == 63) s_w[tid >> 6] = x;
  __syncthreads();
  unsigned woff = 0;
  for (int w = 0; w < (tid >> 6); ++w) woff += s_w[w];
  const unsigned cnt = s_w[0] + s_w[1] + s_w[2] + s_w[3];
  const unsigned thread_excl = woff + (x - c);

  // --- staging: branchless vectorized rec/send, ONE u64 scatter per element ---
  unsigned short rvs[ITEMS], svs[ITEMS];
  if (full && is64) {
    const long long* rp = (const long long*)rec32 + base;
    const long long* sp = (const long long*)send32 + base;
    const ulonglong2 r01 = *(const ulonglong2*)rp;
    const ulonglong2 r23 = *(const ulonglong2*)(rp + 2);
    const ulonglong2 t01 = *(const ulonglong2*)sp;
    const ulonglong2 t23 = *(const ulonglong2*)(sp + 2);
    rvs[0] = (unsigned short)r01.x; rvs[1] = (unsigned short)r01.y;
    rvs[2] = (unsigned short)r23.x; rvs[3] = (unsigned short)r23.y;
    svs[0] = (unsigned short)t01.x; svs[1] = (unsigned short)t01.y;
    svs[2] = (unsigned short)t23.x; svs[3] = (unsigned short)t23.y;
  } else if (full) {
    const uint4 rr = *(const uint4*)((const unsigned*)rec32 + base);
    const uint4 ss = *(const uint4*)((const unsigned*)send32 + base);
    rvs[0] = (unsigned short)rr.x; rvs[1] = (unsigned short)rr.y;
    rvs[2] = (unsigned short)rr.z; rvs[3] = (unsigned short)rr.w;
    svs[0] = (unsigned short)ss.x; svs[1] = (unsigned short)ss.y;
    svs[2] = (unsigned short)ss.z; svs[3] = (unsigned short)ss.w;
  } else {
#pragma unroll
    for (int j = 0; j < 4; ++j) {
      const long long i = base + j;
      unsigned short rv = sent16, sv = sent16;
      if (i < (long long)E) {
        if (is64) {
          rv = (unsigned short)((const long long*)rec32)[i];
          sv = (unsigned short)((const long long*)send32)[i];
        } else {
          rv = (unsigned short)rec32[i];
          sv = (unsigned short)send32[i];
        }
      }
      rvs[j] = rv; svs[j] = sv;
    }
  }
#pragma unroll
  for (int j = 0; j < ITEMS; ++j) {
    const int li = tid * ITEMS + j;
    if (li >= local_n) break;
    const bool act = ((m >> j) & 1u) != 0u;
    const unsigned rb = __popc(m & ((1u << j) - 1u));
    const unsigned actsBefore = thread_excl + rb;
    const unsigned dr = act ? actsBefore : (cnt + ((unsigned)li - actsBefore));
    const unsigned lo = act ? ((unsigned)rvs[j] | ((unsigned)svs[j] << 16))
                            : ((unsigned)sent16 | ((unsigned)sent16 << 16));
    s_pk[dr] = (unsigned long long)lo | ((unsigned long long)li << 32);
  }

  // --- deferred prefix reduce (loads already in flight/retired) ---
  {
    unsigned long long pr = 0;  // low 32: prefix before b; high 32: total
#pragma unroll
    for (int k = 0; k < NK; ++k) {
      const int idx = tid + k * BLOCK;
      pr += ((unsigned long long)bs_v[k] << 32);
      if (idx < b) pr += bs_v[k];
    }
#pragma unroll
    for (int d = 1; d < 64; d <<= 1) pr += __shfl_xor(pr, d);
    if ((tid & 63) == 0) s_red[tid >> 6] = pr;
  }
  __syncthreads();

  const unsigned long long tt = s_red[0] + s_red[1] + s_red[2] + s_red[3];
  const unsigned gA = (unsigned)(tt & 0xffffffffull);
  const unsigned nA = (unsigned)(tt >> 32);
  const unsigned gI = nA + (unsigned)tileBase - gA;

  float* __restrict__ out_na = out;
  float* __restrict__ out_rec = out + (size_t)E;
  float* __restrict__ out_send = out + 2 * (size_t)E;
  float* __restrict__ out_edges = out + 3 * (size_t)E;
  const f4v zero4 = {0.f, 0.f, 0.f, 0.f};
  const int sub = tid & 3;

  if (local_n == TILE) {
#pragma unroll
    for (int k = 0; k < ITEMS; ++k) {
      const int r = tid + k * BLOCK;
      const bool ra = (unsigned)r < cnt;
      const unsigned dest = ra ? (gA + (unsigned)r) : (gI + ((unsigned)r - cnt));
      const unsigned long long pk = s_pk[r];
      __builtin_nontemporal_store(ra ? 1.0f : 0.0f, out_na + dest);
      __builtin_nontemporal_store((float)(pk & 0xffffu), out_rec + dest);
      __builtin_nontemporal_store((float)((pk >> 16) & 0xffffu), out_send + dest);
    }
#pragma unroll 8
    for (int k = 0; k < TILE / (BLOCK / 4); ++k) {  // 16 iters, 4 lanes/row
      const int r = (tid >> 2) + k * (BLOCK / 4);
      const bool ra = (unsigned)r < cnt;
      const unsigned dest = ra ? (gA + (unsigned)r) : (gI + ((unsigned)r - cnt));
      f4v v = zero4;
      if (ra) {
        const int si = (int)(s_pk[r] >> 32);
        v = ((const f4v*)edges)[(size_t)(tileBase + si) * 4 + sub];
      }
      __builtin_nontemporal_store(v, (f4v*)out_edges + (size_t)dest * 4 + sub);
    }
  } else {
    for (int k = 0; k < ITEMS; ++k) {
      const int r = tid + k * BLOCK;
      if (r >= local_n) break;
      const bool ra = (unsigned)r < cnt;
      const unsigned dest = ra ? (gA + (unsigned)r) : (gI + ((unsigned)r - cnt));
      const unsigned long long pk = s_pk[r];
      out_na[dest] = ra ? 1.0f : 0.0f;
      out_rec[dest] = (float)(pk & 0xffffu);
      out_send[dest] = (float)((pk >> 16) & 0xffffu);
    }
    for (int k = 0; k < TILE / (BLOCK / 4); ++k) {
      const int r = (tid >> 2) + k * (BLOCK / 4);
      if (r >= local_n) break;
      const bool ra = (unsigned)r < cnt;
      const unsigned dest = ra ? (gA + (unsigned)r) : (gI + ((unsigned)r - cnt));
      f4v v = zero4;
      if (ra) {
        const int si = (int)(s_pk[r] >> 32);
        v = ((const f4v*)edges)[(size_t)(tileBase + si) * 4 + sub];
      }
      ((f4v*)out_edges)[(size_t)dest * 4 + sub] = v;
    }
  }
}

extern "C" void kernel_launch(void* const* d_in, const int* in_sizes, int n_in,
                              void* d_out, int out_size, void* d_ws, size_t ws_size,
                              hipStream_t stream) {
  const float* edges = (const float*)d_in[1];
  const float* aedges = (const float*)d_in[2];
  const float* uw = (const float*)d_in[3];
  const float* ue = (const float*)d_in[4];
  const int* rec = (const int*)d_in[5];
  const int* send = (const int*)d_in[6];
  const int* timep = (const int*)d_in[7];

  const int E = in_sizes[2];
  const int n_nodes = in_sizes[0] / 128;
  const int sentinel = n_nodes - 1;
  const int nblocks = (E + TILE - 1) / TILE;

  unsigned* bsums = (unsigned*)d_ws;                     // nblocks uints (raw counts)
  unsigned* flagp = bsums + (nblocks + 2);               // dtype flag
  unsigned char* masks = (unsigned char*)(bsums + nblocks + 16);
  const size_t need = (size_t)(nblocks + 16) * 4 + (size_t)nblocks * BLOCK + 64;
  const int use_masks = (ws_size >= need) ? 1 : 0;
  float* out = (float*)d_out;

  hipLaunchKernelGGL(passA, dim3(nblocks), dim3(BLOCK), 0, stream,
                     aedges, ue, uw, timep, (const unsigned*)rec,
                     (const unsigned*)send, bsums, masks, flagp, use_masks, E);
  hipLaunchKernelGGL(passC, dim3(nblocks), dim3(BLOCK), 0, stream,
                     aedges, ue, uw, timep, rec, send, edges, bsums, nblocks,
                     flagp, masks, use_masks, out, E, sentinel);
}